// Round 10
// baseline (123.509 us; speedup 1.0000x reference)
//
#include <hip/hip_runtime.h>
#include <math.h>

// ---------------------------------------------------------------------------
// HybridQuantumDQN: encoder MLP -> 8-qubit statevector sim -> decoder MLP.
// Round 10: MFMA reformulation. One sample per wave64. State = 16x16 complex
// matrix S[r][c] (r = amp bits 7..4, c = bits 3..0), held as an f16 MFMA
// A-fragment: lane(L=lane&15, q=lane>>4) holds A[m=L][k=q*8+j], k=2c+p
// (re/im interleave) -> 4 complex amps S[L][q*4+u].
// A layer = (wires 4-7 on cols: S <- S*U_c^T) then (wires 0-3 on rows, via
// transpose: S^T <- S^T*U_r^T) then CZ diagonal. Each complex matmul = two
// v_mfma_f32_16x16x32_f16 (B = [M_re;-M_im] / [M_im;M_re] interleaved on k).
// KEY: the MFMA C/D layout (lane holds rows q*4+reg of column L) IS the
// A-layout of the transposed next matmul -> zero-exchange chaining, only
// f32->f16 cvt between halves. Orientation restores every full layer.
// B fragments (16x16 Kronecker of four SU(2) gates) built per-lane from the
// wave's 8 fused gates (broadcast via 128B LDS). CZ = per-lane +-1 on D.
// Layer 0 = analytic product state in A-layout. Final RY = same machinery
// with real gates, no CZ. Encoder/decoder lane-split as before (f32).
// ---------------------------------------------------------------------------

#define PI_F 3.14159265358979323846f

typedef _Float16 f16;
typedef f16 half8 __attribute__((ext_vector_type(8)));
typedef float floatx4 __attribute__((ext_vector_type(4)));

struct C2 { float re, im; };
__device__ __forceinline__ C2 cmul(C2 a, C2 b) {
    C2 r;
    r.re = fmaf(a.re, b.re, -a.im * b.im);
    r.im = fmaf(a.re, b.im,  a.im * b.re);
    return r;
}

// Gate G = [[a, -conj(b)], [b, conj(a)]] from packed float4 (ar,ai,br,bi).
__device__ __forceinline__ C2 gsel0(float4 g, int i) {   // column 0: i? b : a
    C2 r; r.re = i ? g.z : g.x; r.im = i ? g.w : g.y; return r;
}
__device__ __forceinline__ C2 gsel1(float4 g, int i) {   // column 1: i? conj(a) : -conj(b)
    C2 r; r.re = i ? g.x : -g.z; r.im = i ? -g.y : g.w; return r;
}
__device__ __forceinline__ C2 gselrt(float4 g, int i, int j) {  // runtime j
    C2 a = gsel0(g, i), b = gsel1(g, i);
    C2 r; r.re = j ? b.re : a.re; r.im = j ? b.im : a.im; return r;
}

// Build B_re/B_im fragments for one half-layer.
// E[u] = GA[iA][jA] * GB[iB][jB] * GC[iC][u>>1] * GD[iD][u&1], u=0..3
// B_re[k=2u]=E_re, B_re[2u+1]=-E_im ; B_im[2u]=E_im, B_im[2u+1]=E_re.
__device__ __forceinline__ void buildB(float4 ga, float4 gb, float4 gc, float4 gd,
                                       int iA, int iB, int iC, int iD,
                                       int jA, int jB,
                                       half8& Bre, half8& Bim) {
    C2 sA = gselrt(ga, iA, jA);
    C2 sB = gselrt(gb, iB, jB);
    C2 P = cmul(sA, sB);
    C2 c0 = gsel0(gc, iC), c1 = gsel1(gc, iC);
    C2 d0 = gsel0(gd, iD), d1 = gsel1(gd, iD);
    C2 E0 = cmul(P, cmul(c0, d0));
    C2 E1 = cmul(P, cmul(c0, d1));
    C2 E2 = cmul(P, cmul(c1, d0));
    C2 E3 = cmul(P, cmul(c1, d1));
    Bre[0] = (f16)E0.re; Bre[1] = (f16)(-E0.im);
    Bre[2] = (f16)E1.re; Bre[3] = (f16)(-E1.im);
    Bre[4] = (f16)E2.re; Bre[5] = (f16)(-E2.im);
    Bre[6] = (f16)E3.re; Bre[7] = (f16)(-E3.im);
    Bim[0] = (f16)E0.im; Bim[1] = (f16)E0.re;
    Bim[2] = (f16)E1.im; Bim[3] = (f16)E1.re;
    Bim[4] = (f16)E2.im; Bim[5] = (f16)E2.re;
    Bim[6] = (f16)E3.im; Bim[7] = (f16)E3.re;
}

__global__ __launch_bounds__(256) void qdqn_kernel(
    const float* __restrict__ x,
    const float* __restrict__ ew1, const float* __restrict__ eb1,
    const float* __restrict__ ew2, const float* __restrict__ eb2,
    const float* __restrict__ qw,
    const float* __restrict__ dw1, const float* __restrict__ db1,
    const float* __restrict__ dw2, const float* __restrict__ db2,
    float* __restrict__ out, int B, int NL) {
    __shared__ __align__(16) float c_lds[32 * 4];
    __shared__ __align__(16) float gx[4][8][4];   // per-wave fused gates
    __shared__ __align__(16) float hx[4][8];      // encoder/decoder exchange

    const int tid = threadIdx.x;
    const int wave = tid >> 6;
    const int lane = tid & 63;
    const int L = lane & 15;
    const int q = lane >> 4;
    int s = blockIdx.x * 4 + wave;          // one sample per wave
    if (s >= B) s = B - 1;

    // ---- Rot SU(2) coeffs once per block: a = e^{-iA}c, b = e^{-iB}s ----
    const int n_gates = NL * 8;
    if (tid < n_gates) {
        const int gg = tid;
        float phi = qw[3 * gg + 0], th = qw[3 * gg + 1], om = qw[3 * gg + 2];
        float c = __cosf(0.5f * th), sv = __sinf(0.5f * th);
        float A = 0.5f * (phi + om), Bb = 0.5f * (phi - om);
        float* o = c_lds + 4 * gg;
        o[0] =  __cosf(A) * c;   o[1] = -__sinf(A) * c;
        o[2] =  __cosf(Bb) * sv; o[3] = -__sinf(Bb) * sv;
    }
    __syncthreads();

    // ---------------- encoder MLP (lane-split over 8 rows) -----------------
    float cqv = 1.0f, sqv = 0.0f;           // this lane's qubit (lanes 0..7)
    {
        float xv[16];
        const float4* xp = (const float4*)(x + s * 16);
#pragma unroll
        for (int i = 0; i < 4; i++) {
            float4 v = xp[i];
            xv[4*i] = v.x; xv[4*i+1] = v.y; xv[4*i+2] = v.z; xv[4*i+3] = v.w;
        }
        const int r = lane & 7;
        float a = eb1[r];
#pragma unroll
        for (int i = 0; i < 16; i++) a = fmaf(ew1[r * 16 + i], xv[i], a);
        if (lane < 8) hx[wave][r] = fmaxf(a, 0.0f);
        __builtin_amdgcn_wave_barrier();
        float4 h01 = *(const float4*)&hx[wave][0];
        float4 h23 = *(const float4*)&hx[wave][4];
        float b = eb2[r];
        b = fmaf(ew2[r*8+0], h01.x, b); b = fmaf(ew2[r*8+1], h01.y, b);
        b = fmaf(ew2[r*8+2], h01.z, b); b = fmaf(ew2[r*8+3], h01.w, b);
        b = fmaf(ew2[r*8+4], h23.x, b); b = fmaf(ew2[r*8+5], h23.y, b);
        b = fmaf(ew2[r*8+6], h23.z, b); b = fmaf(ew2[r*8+7], h23.w, b);
        float e = 1.0f - __fdividef(2.0f, __expf(2.0f * b) + 1.0f);  // tanh
        float ang = e * (0.5f * PI_F);
        cqv = __cosf(ang);
        sqv = __sinf(ang);
    }

    // ---- CZ signs per lane: amp (r=L, c=q*4+u) ----
    const int L0 = L & 1, L1b = (L >> 1) & 1, L2b = (L >> 2) & 1, L3b = (L >> 3) & 1;
    const int c3 = (q >> 1) & 1, c2 = q & 1;
    const int pr = (L3b & L2b) ^ (L2b & L1b) ^ (L1b & L0);
    const int cross = L0 & c3;
    float czs[4];
#pragma unroll
    for (int u = 0; u < 4; u++) {
        int c1 = (u >> 1) & 1, c0 = u & 1;
        int pc = (c3 & c2) ^ (c2 & c1) ^ (c1 & c0);
        czs[u] = ((pr ^ cross ^ pc) & 1) ? -1.0f : 1.0f;
    }

    const int iA = L3b, iB = L2b, iC = L1b, iD = L0;   // L bits 3..0
    const int jA = c3, jB = c2;                        // q bits

    half8 A;
    floatx4 dre, dim;
    const floatx4 zf = {0.0f, 0.0f, 0.0f, 0.0f};

    for (int l = 0; l <= NL; l++) {
        // ---- lanes 0..7 build fused gate (a,b) for qubit = lane ----
        if (lane < 8) {
            float ar, ai, br, bi;
            if (l < NL) {
                const float4 c0 = *(const float4*)(c_lds + 4 * (l * 8 + lane));
                ar = fmaf(c0.x, cqv, -c0.z * sqv);
                ai = fmaf(c0.y, cqv,  c0.w * sqv);
                br = fmaf(c0.z, cqv,  c0.x * sqv);
                bi = fmaf(c0.w, cqv, -c0.y * sqv);
            } else {           // final RY layer: real gate
                ar = cqv; ai = 0.0f; br = sqv; bi = 0.0f;
            }
            *(float4*)gx[wave][lane] = make_float4(ar, ai, br, bi);
        }
        __builtin_amdgcn_wave_barrier();

        if (l == 0) {
            // ---- analytic product state into A-layout, CZ folded ----
            float4 g0 = *(const float4*)gx[wave][0];
            float4 g1 = *(const float4*)gx[wave][1];
            float4 g2 = *(const float4*)gx[wave][2];
            float4 g3 = *(const float4*)gx[wave][3];
            float4 g4 = *(const float4*)gx[wave][4];
            float4 g5 = *(const float4*)gx[wave][5];
            float4 g6 = *(const float4*)gx[wave][6];
            float4 g7 = *(const float4*)gx[wave][7];
            C2 Pr = cmul(cmul(gsel0(g0, iA), gsel0(g1, iB)),
                         cmul(gsel0(g2, iC), gsel0(g3, iD)));
            C2 Pc = cmul(gsel0(g4, jA), gsel0(g5, jB));
            C2 P = cmul(Pr, Pc);
            C2 t60 = gsel0(g6, 0), t61 = gsel0(g6, 1);
            C2 t70 = gsel0(g7, 0), t71 = gsel0(g7, 1);
            C2 T[4] = { cmul(t60, t70), cmul(t60, t71),
                        cmul(t61, t70), cmul(t61, t71) };
#pragma unroll
            for (int u = 0; u < 4; u++) {
                C2 E = cmul(P, T[u]);
                A[2*u]   = (f16)(E.re * czs[u]);
                A[2*u+1] = (f16)(E.im * czs[u]);
            }
            continue;
        }

        // ---- half 1: wires 4..7 act on cols; S <- S * U_c^T ----
        {
            float4 g4 = *(const float4*)gx[wave][4];
            float4 g5 = *(const float4*)gx[wave][5];
            float4 g6 = *(const float4*)gx[wave][6];
            float4 g7 = *(const float4*)gx[wave][7];
            half8 Bre, Bim;
            buildB(g4, g5, g6, g7, iA, iB, iC, iD, jA, jB, Bre, Bim);
            dre = __builtin_amdgcn_mfma_f32_16x16x32_f16(A, Bre, zf, 0, 0, 0);
            dim = __builtin_amdgcn_mfma_f32_16x16x32_f16(A, Bim, zf, 0, 0, 0);
            // D1[r][c], lane holds rows q*4+u of col L == A-layout of S'^T
#pragma unroll
            for (int u = 0; u < 4; u++) {
                A[2*u]   = (f16)dre[u];
                A[2*u+1] = (f16)dim[u];
            }
        }
        // ---- half 2: wires 0..3 act on rows; S^T <- S^T * U_r^T ----
        {
            float4 g0 = *(const float4*)gx[wave][0];
            float4 g1 = *(const float4*)gx[wave][1];
            float4 g2 = *(const float4*)gx[wave][2];
            float4 g3 = *(const float4*)gx[wave][3];
            half8 Bre, Bim;
            buildB(g0, g1, g2, g3, iA, iB, iC, iD, jA, jB, Bre, Bim);
            dre = __builtin_amdgcn_mfma_f32_16x16x32_f16(A, Bre, zf, 0, 0, 0);
            dim = __builtin_amdgcn_mfma_f32_16x16x32_f16(A, Bim, zf, 0, 0, 0);
            if (l < NL) {   // CZ diagonal (skip after final RY layer)
#pragma unroll
                for (int u = 0; u < 4; u++) { dre[u] *= czs[u]; dim[u] *= czs[u]; }
            }
            if (l < NL) {   // repack for next layer (last layer keeps dre/dim)
#pragma unroll
                for (int u = 0; u < 4; u++) {
                    A[2*u]   = (f16)dre[u];
                    A[2*u+1] = (f16)dim[u];
                }
            }
        }
    }

    // ---------------- probs -> <Z_w> ----------------
    // lane holds amps (r=L, c=q*4+u) in dre/dim (f32).
    float p0 = fmaf(dre[0], dre[0], dim[0] * dim[0]);
    float p1 = fmaf(dre[1], dre[1], dim[1] * dim[1]);
    float p2 = fmaf(dre[2], dre[2], dim[2] * dim[2]);
    float p3 = fmaf(dre[3], dre[3], dim[3] * dim[3]);
    float sumP = (p0 + p1) + (p2 + p3);

    float zW[8];
    zW[0] = L3b ? -sumP : sumP;            // wire0 <- r bit3
    zW[1] = L2b ? -sumP : sumP;
    zW[2] = L1b ? -sumP : sumP;
    zW[3] = L0  ? -sumP : sumP;
    zW[4] = c3  ? -sumP : sumP;            // wire4 <- c bit3 (lane-const)
    zW[5] = c2  ? -sumP : sumP;
    zW[6] = (p0 + p1) - (p2 + p3);         // c bit1 = u>>1
    zW[7] = (p0 - p1) + (p2 - p3);         // c bit0 = u&1

#pragma unroll
    for (int m = 1; m < 64; m <<= 1) {
#pragma unroll
        for (int w = 0; w < 8; w++) zW[w] += __shfl_xor(zW[w], m, 64);
    }

    // ---------------- decoder MLP (lane-split) ----------------
    {
        const int r = lane & 7;
        float a = db1[r];
#pragma unroll
        for (int w = 0; w < 8; w++) a = fmaf(dw1[r * 8 + w], zW[w], a);
        if (lane < 8) hx[wave][r] = fmaxf(a, 0.0f);
        __builtin_amdgcn_wave_barrier();
        if (lane < 4) {
            float4 h01 = *(const float4*)&hx[wave][0];
            float4 h23 = *(const float4*)&hx[wave][4];
            float acc = db2[lane];
            acc = fmaf(dw2[lane*8+0], h01.x, acc); acc = fmaf(dw2[lane*8+1], h01.y, acc);
            acc = fmaf(dw2[lane*8+2], h01.z, acc); acc = fmaf(dw2[lane*8+3], h01.w, acc);
            acc = fmaf(dw2[lane*8+4], h23.x, acc); acc = fmaf(dw2[lane*8+5], h23.y, acc);
            acc = fmaf(dw2[lane*8+6], h23.z, acc); acc = fmaf(dw2[lane*8+7], h23.w, acc);
            out[s * 4 + lane] = acc;
        }
    }
}

extern "C" void kernel_launch(void* const* d_in, const int* in_sizes, int n_in,
                              void* d_out, int out_size, void* d_ws, size_t ws_size,
                              hipStream_t stream) {
    const float* x   = (const float*)d_in[0];
    const float* ew1 = (const float*)d_in[1];
    const float* eb1 = (const float*)d_in[2];
    const float* ew2 = (const float*)d_in[3];
    const float* eb2 = (const float*)d_in[4];
    const float* qw  = (const float*)d_in[5];
    const float* dw1 = (const float*)d_in[6];
    const float* db1 = (const float*)d_in[7];
    const float* dw2 = (const float*)d_in[8];
    const float* db2 = (const float*)d_in[9];
    float* out = (float*)d_out;

    int B = in_sizes[0] / 16;        // 32768
    int n_gates = in_sizes[5] / 3;   // 32
    int NL = n_gates / 8;            // 4

    // one sample per wave; 4 waves per 256-thread block -> 8192 blocks
    int blocks = (B + 3) / 4;
    qdqn_kernel<<<blocks, 256, 0, stream>>>(x, ew1, eb1, ew2, eb2, qw,
                                            dw1, db1, dw2, db2, out, B, NL);
}

// Round 11
// 117.011 us; speedup vs baseline: 1.0555x; 1.0555x over previous
//
#include <hip/hip_runtime.h>
#include <math.h>

// ---------------------------------------------------------------------------
// HybridQuantumDQN: encoder MLP -> 8-qubit statevector sim -> decoder MLP.
// FINAL (= Round 7, session best: 58.2 us). 8 samples/wave64; 8 lanes/sample;
// 32 complex amps/lane (v2f); packed fp32 v_pk_fma_f32 for all state math.
// Sample's 8 lanes on lane bits {0,1,3} so ALL cross-wire exchanges are DPP
// (xor1/xor2 = quad_perm, xor8 = row_ror:8). Cross-wire updates chunked:
// gather 8 regs' partners via DPP, then the 32 pk ops. amp = (G<<5)|t:
// G = lane bits {3,1,0} (amp bits 7..5), t = reg idx (amp bits 4..0).
// Wires 0..2 cross (xor8/2/1), 3..7 in-lane. Encoder/decoder/transcendentals
// split across the sample's 8 lanes via tiny wave-local LDS exchanges.
// Layer 0 = product state. CZ = closed-form +-1 diagonal.
//
// Session conclusions (measured, rounds 1-10):
//  - VALU-issue/pipe bound: ~68 TF eff = ~66% of the practical fp32-VALU
//    ceiling; pk inst count is at the algebraic minimum (8 pk/complex pair).
//  - More residency does NOT help (R9: 2.6 vs 1.8 waves/SIMD, slightly worse
//    due to +8% exchange insts). LDS transposes (R4) and ds_swizzle vs DPP
//    (R6 vs R7) are within ~1%.
//  - MFMA reformulation (R10) is correct but SLOWER (65.8 us): building the
//    16x16 Kronecker B-fragments costs as much VALU as applying the gates.
//  - launch_bounds min-waves >4 forces VGPR < state size -> scratch spill
//    (R8: 100 MB HBM round-trips). Keep (128, 2).
// ---------------------------------------------------------------------------

#define PI_F 3.14159265358979323846f

typedef float v2f __attribute__((ext_vector_type(2)));

struct C2 { float re, im; };
__device__ __forceinline__ C2 cmul(C2 a, C2 b) {
    C2 r;
    r.re = fmaf(a.re, b.re, -a.im * b.im);
    r.im = fmaf(a.re, b.im,  a.im * b.re);
    return r;
}
__device__ __forceinline__ float fxor(float x, int m) {
    return __int_as_float(__float_as_int(x) ^ m);
}

// ---------------- packed fp32 primitives (VOP3P) ----------------
__device__ __forceinline__ v2f pk_mul(v2f a, v2f b) {
    v2f d; asm("v_pk_mul_f32 %0, %1, %2" : "=v"(d) : "v"(a), "v"(b)); return d;
}
__device__ __forceinline__ v2f pk_mul_neg(v2f a, v2f b) {
    v2f d; asm("v_pk_mul_f32 %0, %1, %2 neg_lo:[1,0] neg_hi:[1,0]"
               : "=v"(d) : "v"(a), "v"(b)); return d;
}
__device__ __forceinline__ v2f pk_fma(v2f a, v2f b, v2f c) {
    v2f d; asm("v_pk_fma_f32 %0, %1, %2, %3" : "=v"(d) : "v"(a), "v"(b), "v"(c)); return d;
}
// d = -(a*b) + c
__device__ __forceinline__ v2f pk_fma_nn(v2f a, v2f b, v2f c) {
    v2f d; asm("v_pk_fma_f32 %0, %1, %2, %3 neg_lo:[1,0,0] neg_hi:[1,0,0]"
               : "=v"(d) : "v"(a), "v"(b), "v"(c)); return d;
}
// d.lo = -a.lo*b.hi + c.lo ; d.hi = a.hi*b.lo + c.hi   (complex cross term)
__device__ __forceinline__ v2f pk_fma_swl(v2f a, v2f b, v2f c) {
    v2f d; asm("v_pk_fma_f32 %0, %1, %2, %3 op_sel:[0,1,0] op_sel_hi:[1,0,1] neg_lo:[1,0,0]"
               : "=v"(d) : "v"(a), "v"(b), "v"(c)); return d;
}
// d.lo = a.lo*b.hi + c.lo ; d.hi = -a.hi*b.lo + c.hi
__device__ __forceinline__ v2f pk_fma_swh(v2f a, v2f b, v2f c) {
    v2f d; asm("v_pk_fma_f32 %0, %1, %2, %3 op_sel:[0,1,0] op_sel_hi:[1,0,1] neg_hi:[1,0,0]"
               : "=v"(d) : "v"(a), "v"(b), "v"(c)); return d;
}
// z * (re + i*im), complex scalar in C2
__device__ __forceinline__ v2f cmulv(v2f z, C2 c) {
    v2f n = pk_mul((v2f){c.re, c.re}, z);
    return pk_fma_swl((v2f){c.im, c.im}, z, n);
}

// ---------------- cross-lane exchange (all DPP) ----------------
template<int CTRL>
__device__ __forceinline__ float dppf(float x) {
    int xi = __float_as_int(x);
    int r = __builtin_amdgcn_update_dpp(xi, xi, CTRL, 0xF, 0xF, false);
    return __int_as_float(r);
}
template<int M>
__device__ __forceinline__ float lxor(float x) {
    if constexpr (M == 1)      return dppf<0xB1>(x);   // quad_perm [1,0,3,2]
    else if constexpr (M == 2) return dppf<0x4E>(x);   // quad_perm [2,3,0,1]
    else                       return dppf<0x128>(x);  // row_ror:8 == lane^8 in row16
}

// ---------------- gates ----------------
// fused SU(2) gate G = Rot * RY: columns (a,b); G = [[a,-conj(b)],[b,conj(a)]]
__device__ __forceinline__ void load_G2(const float* __restrict__ c_lds, int g,
                                        float cc, float ss,
                                        float& ar, float& ai, float& br, float& bi) {
    const float4 c0 = *(const float4*)(c_lds + 4 * g);  // aR.re aR.im bR.re bR.im
    ar = fmaf(c0.x, cc, -c0.z * ss);
    ai = fmaf(c0.y, cc,  c0.w * ss);
    br = fmaf(c0.z, cc,  c0.x * ss);
    bi = fmaf(c0.w, cc, -c0.y * ss);
}

// cross-lane SU(2): new = cS*z + cO*p, coefficients pre-sign-adjusted per lane
// (lo lane: cS=(ar,ai), cO=(-br,bi); hi lane: cS=(ar,-ai), cO=(br,bi))
// Chunked: gather 8 regs' partners via DPP, then the 32 pk ops.
template<int M>
__device__ __forceinline__ void su2_cross(v2f cSr, v2f cSi, v2f cOr, v2f cOi,
                                          v2f z[32]) {
#pragma unroll
    for (int c = 0; c < 4; c++) {
        v2f p[8];
#pragma unroll
        for (int k = 0; k < 8; k++) {
            p[k].x = lxor<M>(z[c * 8 + k].x);
            p[k].y = lxor<M>(z[c * 8 + k].y);
        }
#pragma unroll
        for (int k = 0; k < 8; k++) {
            const int t = c * 8 + k;
            v2f n = pk_mul(cSr, z[t]);
            n = pk_fma_swl(cSi, z[t], n);
            n = pk_fma   (cOr, p[k], n);
            n = pk_fma_swl(cOi, p[k], n);
            z[t] = n;
        }
    }
}

// in-lane SU(2) on reg-index bit ST
template<int ST>
__device__ __forceinline__ void su2_inlane(v2f arr, v2f aii, v2f brr, v2f bii,
                                           v2f z[32]) {
#pragma unroll
    for (int t = 0; t < 32; t++) {
        if ((t & ST) == 0) {
            const int u = t + ST;
            v2f x = z[t], y = z[u];
            v2f nx = pk_mul(arr, x);
            nx = pk_fma_swl(aii, x, nx);
            nx = pk_fma_nn (brr, y, nx);
            nx = pk_fma_swl(bii, y, nx);
            v2f ny = pk_mul(brr, x);
            ny = pk_fma_swl(bii, x, ny);
            ny = pk_fma   (arr, y, ny);
            ny = pk_fma_swh(aii, y, ny);
            z[t] = nx; z[u] = ny;
        }
    }
}

// final RY: cross (cO pre-signed per lane), chunked like su2_cross
template<int M>
__device__ __forceinline__ void ry_cross(v2f cc, v2f cO, v2f z[32]) {
#pragma unroll
    for (int c = 0; c < 4; c++) {
        v2f p[8];
#pragma unroll
        for (int k = 0; k < 8; k++) {
            p[k].x = lxor<M>(z[c * 8 + k].x);
            p[k].y = lxor<M>(z[c * 8 + k].y);
        }
#pragma unroll
        for (int k = 0; k < 8; k++) {
            const int t = c * 8 + k;
            z[t] = pk_fma(cO, p[k], pk_mul(cc, z[t]));
        }
    }
}
template<int ST>
__device__ __forceinline__ void ry_inlane(v2f cc, v2f ss, v2f z[32]) {
#pragma unroll
    for (int t = 0; t < 32; t++) {
        if ((t & ST) == 0) {
            const int u = t + ST;
            v2f x = z[t], y = z[u];
            z[t] = pk_fma_nn(ss, y, pk_mul(cc, x));   // c*x - s*y
            z[u] = pk_fma   (cc, y, pk_mul(ss, x));   // s*x + c*y
        }
    }
}

// CZ t-part (5-bit): parity of adjacent-bit ANDs
__host__ __device__ constexpr bool czt5(int t) {
    return ((((t >> 4) & (t >> 3)) ^ ((t >> 3) & (t >> 2)) ^
             ((t >> 2) & (t >> 1)) ^ ((t >> 1) & t)) & 1) != 0;
}

__global__ __launch_bounds__(128, 2) void qdqn_kernel(
    const float* __restrict__ x,
    const float* __restrict__ ew1, const float* __restrict__ eb1,
    const float* __restrict__ ew2, const float* __restrict__ eb2,
    const float* __restrict__ qw,
    const float* __restrict__ dw1, const float* __restrict__ db1,
    const float* __restrict__ dw2, const float* __restrict__ db2,
    float* __restrict__ out, int B, int NL) {
    __shared__ __align__(16) float c_lds[32 * 4];
    __shared__ __align__(16) float hx[2][8][8];     // h / h2 exchange
    __shared__ __align__(16) float csx[2][8][16];   // (c,s) exchange

    const int tid = threadIdx.x;
    const int wave = tid >> 6;
    const int lane = tid & 63;
    // sample lane bits {0,1,3}; sample id bits {2,4,5} -> all-DPP cross wires
    const int g = (lane & 3) | ((lane >> 1) & 4);          // amp bits 7..5
    const int grp = ((lane >> 2) & 1) | ((lane >> 3) & 6); // sample in wave
    int s = blockIdx.x * 16 + wave * 8 + grp;
    if (s >= B) s = B - 1;

    // ---- prefetch x early (overlaps coef computation + barrier) ----
    float xv[16];
    {
        const float4* xp = (const float4*)(x + s * 16);
#pragma unroll
        for (int i = 0; i < 4; i++) {
            float4 v = xp[i];
            xv[4*i] = v.x; xv[4*i+1] = v.y; xv[4*i+2] = v.z; xv[4*i+3] = v.w;
        }
    }

    // ---- Rot SU(2) coeffs once per block: a = e^{-iA}c, b = e^{-iB}s ----
    const int n_gates = NL * 8;
    if (tid < n_gates) {
        const int gg = tid;
        float phi = qw[3 * gg + 0], th = qw[3 * gg + 1], om = qw[3 * gg + 2];
        float c = __cosf(0.5f * th), sv = __sinf(0.5f * th);
        float A = 0.5f * (phi + om), Bb = 0.5f * (phi - om);
        float* o = c_lds + 4 * gg;
        o[0] =  __cosf(A) * c;   o[1] = -__sinf(A) * c;
        o[2] =  __cosf(Bb) * sv; o[3] = -__sinf(Bb) * sv;
    }
    __syncthreads();

    // ---------------- encoder MLP, split across the 8 lanes ----------------
    float cq[8], sq[8];
    {
        // lane computes row g of W1
        float a = eb1[g];
#pragma unroll
        for (int i = 0; i < 16; i++) a = fmaf(ew1[g * 16 + i], xv[i], a);
        hx[wave][grp][g] = fmaxf(a, 0.0f);
        __builtin_amdgcn_wave_barrier();
        float4 h01 = *(const float4*)&hx[wave][grp][0];
        float4 h23 = *(const float4*)&hx[wave][grp][4];
        // lane computes qubit g of layer 2 + transcendentals
        float b = eb2[g];
        b = fmaf(ew2[g*8+0], h01.x, b); b = fmaf(ew2[g*8+1], h01.y, b);
        b = fmaf(ew2[g*8+2], h01.z, b); b = fmaf(ew2[g*8+3], h01.w, b);
        b = fmaf(ew2[g*8+4], h23.x, b); b = fmaf(ew2[g*8+5], h23.y, b);
        b = fmaf(ew2[g*8+6], h23.z, b); b = fmaf(ew2[g*8+7], h23.w, b);
        float e = 1.0f - __fdividef(2.0f, __expf(2.0f * b) + 1.0f);  // tanh
        float ang = e * (0.5f * PI_F);
        float2* cso = (float2*)&csx[wave][grp][2 * g];
        *cso = make_float2(__cosf(ang), __sinf(ang));
        __builtin_amdgcn_wave_barrier();
#pragma unroll
        for (int k = 0; k < 4; k++) {
            float4 v = *(const float4*)&csx[wave][grp][4 * k];
            cq[2*k] = v.x; sq[2*k] = v.y; cq[2*k+1] = v.z; sq[2*k+1] = v.w;
        }
    }

    // ---- per-lane sign masks for cross wires q=0..2 (logical bit 2-q of g)
    int hiM[3], loM[3];
#pragma unroll
    for (int q = 0; q < 3; q++) {
        int hi = (g >> (2 - q)) & 1;
        hiM[q] = hi << 31;                 // flips ai when hi lane
        loM[q] = hiM[q] ^ 0x80000000;      // flips br when lo lane
    }

    // ---- CZ lane scalars: amp=(G<<5)|t; pairs (G2&G1)+(G1&G0)+(G0&t4)+t-part
    const int g0b = g & 1, g1b = (g >> 1) & 1, g2b = (g >> 2) & 1;
    const float mLo = ((g2b & g1b) ^ (g1b & g0b)) ? -1.0f : 1.0f;  // t < 16
    const float mHi = g0b ? -mLo : mLo;                            // t >= 16
    const v2f mLo2 = (v2f){mLo, mLo}, mHi2 = (v2f){mHi, mHi};

    // ---------------- layer 0: product state, CZ folded --------------------
    v2f z[32];
    {
        C2 P; P.re = 1.0f; P.im = 0.0f;
        C2 A[5], Bc[5];
#pragma unroll
        for (int q = 0; q < 8; q++) {
            float ar, ai, br, bi;
            load_G2(c_lds, q, cq[q], sq[q], ar, ai, br, bi);
            if (q < 3) {
                const bool hi = (g >> (2 - q)) & 1;
                C2 f; f.re = hi ? br : ar; f.im = hi ? bi : ai;  // column 0
                P = cmul(P, f);
            } else {
                A[q-3].re = ar;  A[q-3].im = ai;
                Bc[q-3].re = br; Bc[q-3].im = bi;
            }
        }
        z[0] = (v2f){P.re, P.im};
#pragma unroll
        for (int w = 0; w < 5; w++) {
            const int n = 1 << w;
#pragma unroll
            for (int i = n - 1; i >= 0; i--) {
                v2f v = z[i];
                z[2*i+1] = cmulv(v, Bc[w]);
                z[2*i]   = cmulv(v, A[w]);
            }
        }
#pragma unroll
        for (int t = 0; t < 32; t++) {
            v2f m = (t < 16) ? mLo2 : mHi2;
            z[t] = czt5(t) ? pk_mul_neg(m, z[t]) : pk_mul(m, z[t]);
        }
    }

    // ---------------- layers 1..NL-1 ---------------------------------------
    for (int l = 1; l < NL; l++) {
        const int gb = l * 8;
        float ar, ai, br, bi;
        load_G2(c_lds, gb+0, cq[0], sq[0], ar, ai, br, bi);
        su2_cross<8>((v2f){ar,ar}, (v2f){fxor(ai,hiM[0]),fxor(ai,hiM[0])},
                     (v2f){fxor(br,loM[0]),fxor(br,loM[0])}, (v2f){bi,bi}, z);
        load_G2(c_lds, gb+1, cq[1], sq[1], ar, ai, br, bi);
        su2_cross<2>((v2f){ar,ar}, (v2f){fxor(ai,hiM[1]),fxor(ai,hiM[1])},
                     (v2f){fxor(br,loM[1]),fxor(br,loM[1])}, (v2f){bi,bi}, z);
        load_G2(c_lds, gb+2, cq[2], sq[2], ar, ai, br, bi);
        su2_cross<1>((v2f){ar,ar}, (v2f){fxor(ai,hiM[2]),fxor(ai,hiM[2])},
                     (v2f){fxor(br,loM[2]),fxor(br,loM[2])}, (v2f){bi,bi}, z);
        load_G2(c_lds, gb+3, cq[3], sq[3], ar, ai, br, bi);
        su2_inlane<16>((v2f){ar,ar}, (v2f){ai,ai}, (v2f){br,br}, (v2f){bi,bi}, z);
        load_G2(c_lds, gb+4, cq[4], sq[4], ar, ai, br, bi);
        su2_inlane<8>((v2f){ar,ar}, (v2f){ai,ai}, (v2f){br,br}, (v2f){bi,bi}, z);
        load_G2(c_lds, gb+5, cq[5], sq[5], ar, ai, br, bi);
        su2_inlane<4>((v2f){ar,ar}, (v2f){ai,ai}, (v2f){br,br}, (v2f){bi,bi}, z);
        load_G2(c_lds, gb+6, cq[6], sq[6], ar, ai, br, bi);
        su2_inlane<2>((v2f){ar,ar}, (v2f){ai,ai}, (v2f){br,br}, (v2f){bi,bi}, z);
        load_G2(c_lds, gb+7, cq[7], sq[7], ar, ai, br, bi);
        su2_inlane<1>((v2f){ar,ar}, (v2f){ai,ai}, (v2f){br,br}, (v2f){bi,bi}, z);
        // CZ diagonal
#pragma unroll
        for (int t = 0; t < 32; t++) {
            v2f m = (t < 16) ? mLo2 : mHi2;
            z[t] = czt5(t) ? pk_mul_neg(m, z[t]) : pk_mul(m, z[t]);
        }
    }

    // ---------------- final RY layer ---------------------------------------
    {
        v2f cc, cO, ss;
        cc=(v2f){cq[0],cq[0]}; cO=(v2f){fxor(sq[0],loM[0]),fxor(sq[0],loM[0])};
        ry_cross<8>(cc, cO, z);
        cc=(v2f){cq[1],cq[1]}; cO=(v2f){fxor(sq[1],loM[1]),fxor(sq[1],loM[1])};
        ry_cross<2>(cc, cO, z);
        cc=(v2f){cq[2],cq[2]}; cO=(v2f){fxor(sq[2],loM[2]),fxor(sq[2],loM[2])};
        ry_cross<1>(cc, cO, z);
        cc=(v2f){cq[3],cq[3]}; ss=(v2f){sq[3],sq[3]}; ry_inlane<16>(cc, ss, z);
        cc=(v2f){cq[4],cq[4]}; ss=(v2f){sq[4],sq[4]}; ry_inlane<8>(cc, ss, z);
        cc=(v2f){cq[5],cq[5]}; ss=(v2f){sq[5],sq[5]}; ry_inlane<4>(cc, ss, z);
        cc=(v2f){cq[6],cq[6]}; ss=(v2f){sq[6],sq[6]}; ry_inlane<2>(cc, ss, z);
        cc=(v2f){cq[7],cq[7]}; ss=(v2f){sq[7],sq[7]}; ry_inlane<1>(cc, ss, z);
    }

    // ---------------- probs -> <Z_w> ----------------
    float p[32];
#pragma unroll
    for (int t = 0; t < 32; t++) p[t] = fmaf(z[t].x, z[t].x, z[t].y * z[t].y);

    float s16[16], zW[8];
    {
        float d = 0.0f;
#pragma unroll
        for (int i = 0; i < 16; i++) {
            s16[i] = p[2*i] + p[2*i+1];
            d += p[2*i] - p[2*i+1];
        }
        zW[7] = d;
        float s8[8]; d = 0.0f;
#pragma unroll
        for (int i = 0; i < 8; i++) {
            s8[i] = s16[2*i] + s16[2*i+1];
            d += s16[2*i] - s16[2*i+1];
        }
        zW[6] = d;
        float s4[4]; d = 0.0f;
#pragma unroll
        for (int i = 0; i < 4; i++) {
            s4[i] = s8[2*i] + s8[2*i+1];
            d += s8[2*i] - s8[2*i+1];
        }
        zW[5] = d;
        float s2a = s4[0] + s4[1], s2b = s4[2] + s4[3];
        zW[4] = (s4[0] - s4[1]) + (s4[2] - s4[3]);
        float sumP = s2a + s2b;
        zW[3] = s2a - s2b;
        zW[0] = g2b ? -sumP : sumP;
        zW[1] = g1b ? -sumP : sumP;
        zW[2] = g0b ? -sumP : sumP;
    }
    // all-reduce across the 8 lanes of the sample (bits 0,1,3 -> all DPP)
#pragma unroll
    for (int w = 0; w < 8; w++) zW[w] += lxor<1>(zW[w]);
#pragma unroll
    for (int w = 0; w < 8; w++) zW[w] += lxor<2>(zW[w]);
#pragma unroll
    for (int w = 0; w < 8; w++) zW[w] += lxor<8>(zW[w]);

    // ---------------- decoder MLP, split across lanes ----------------------
    {
        float a = db1[g];
#pragma unroll
        for (int w = 0; w < 8; w++) a = fmaf(dw1[g * 8 + w], zW[w], a);
        hx[wave][grp][g] = fmaxf(a, 0.0f);
        __builtin_amdgcn_wave_barrier();
        float4 h01 = *(const float4*)&hx[wave][grp][0];
        float4 h23 = *(const float4*)&hx[wave][grp][4];
        const int o = g & 3;   // lanes g and g+4 compute identical output o
        float acc = db2[o];
        acc = fmaf(dw2[o*8+0], h01.x, acc); acc = fmaf(dw2[o*8+1], h01.y, acc);
        acc = fmaf(dw2[o*8+2], h01.z, acc); acc = fmaf(dw2[o*8+3], h01.w, acc);
        acc = fmaf(dw2[o*8+4], h23.x, acc); acc = fmaf(dw2[o*8+5], h23.y, acc);
        acc = fmaf(dw2[o*8+6], h23.z, acc); acc = fmaf(dw2[o*8+7], h23.w, acc);
        out[s * 4 + o] = acc;
    }
}

extern "C" void kernel_launch(void* const* d_in, const int* in_sizes, int n_in,
                              void* d_out, int out_size, void* d_ws, size_t ws_size,
                              hipStream_t stream) {
    const float* x   = (const float*)d_in[0];
    const float* ew1 = (const float*)d_in[1];
    const float* eb1 = (const float*)d_in[2];
    const float* ew2 = (const float*)d_in[3];
    const float* eb2 = (const float*)d_in[4];
    const float* qw  = (const float*)d_in[5];
    const float* dw1 = (const float*)d_in[6];
    const float* db1 = (const float*)d_in[7];
    const float* dw2 = (const float*)d_in[8];
    const float* db2 = (const float*)d_in[9];
    float* out = (float*)d_out;

    int B = in_sizes[0] / 16;        // 32768
    int n_gates = in_sizes[5] / 3;   // 32
    int NL = n_gates / 8;            // 4

    // 16 samples per 128-thread block (2 waves x 8 samples/wave)
    int blocks = (B + 15) / 16;
    qdqn_kernel<<<blocks, 128, 0, stream>>>(x, ew1, eb1, ew2, eb2, qw,
                                            dw1, db1, dw2, db2, out, B, NL);
}